// Round 5
// baseline (5360.368 us; speedup 1.0000x reference)
//
#include <hip/hip_runtime.h>
#include <cstdint>

#define H0 192
#define W0 192
#define TT 4
#define NBATCH 6   // both spynet directions batched: n<3 -> fwd, n>=3 -> bwd

// ---------------- normalize ----------------
__global__ void k_normalize(const float* __restrict__ vid, float* __restrict__ nv) {
    int idx = blockIdx.x * 256 + threadIdx.x;
    const int total = TT * 3 * H0 * W0;
    if (idx >= total) return;
    int c = (idx / (H0 * W0)) % 3;
    float m = (c == 0) ? 0.485f : (c == 1) ? 0.456f : 0.406f;
    float s = (c == 0) ? 0.229f : (c == 1) ? 0.224f : 0.225f;
    nv[idx] = (vid[idx] - m) / s;
}

// ---------------- 2x2 average pool ----------------
__global__ void k_pool(const float* __restrict__ in, float* __restrict__ out,
                       int NC, int Ho, int Wo) {
    int idx = blockIdx.x * 256 + threadIdx.x;
    int total = NC * Ho * Wo;
    if (idx >= total) return;
    int x = idx % Wo;
    int y = (idx / Wo) % Ho;
    int nc = idx / (Wo * Ho);
    const float* p = in + ((size_t)nc * (Ho * 2) + y * 2) * (size_t)(Wo * 2) + x * 2;
    int Wi = Wo * 2;
    out[idx] = (p[0] + p[1] + p[Wi] + p[Wi + 1]) * 0.25f;
}

// ---------------- 2x bilinear upsample (jax.image.resize semantics), x2.0 scale ----------------
__global__ void k_upsample2x(const float* __restrict__ in, float* __restrict__ out,
                             int NC, int Hi, int Wi) {
    int Ho = Hi * 2, Wo = Wi * 2;
    int idx = blockIdx.x * 256 + threadIdx.x;
    int total = NC * Ho * Wo;
    if (idx >= total) return;
    int x = idx % Wo;
    int y = (idx / Wo) % Ho;
    int nc = idx / (Wo * Ho);
    int ky = y >> 1, kx = x >> 1;
    int y0, y1, x0, x1;
    float wy0, wy1, wx0, wx1;
    if ((y & 1) == 0) {
        if (ky == 0) { y0 = 0; y1 = 0; wy0 = 1.f; wy1 = 0.f; }
        else { y0 = ky - 1; y1 = ky; wy0 = 0.25f; wy1 = 0.75f; }
    } else {
        if (ky == Hi - 1) { y0 = ky; y1 = ky; wy0 = 1.f; wy1 = 0.f; }
        else { y0 = ky; y1 = ky + 1; wy0 = 0.75f; wy1 = 0.25f; }
    }
    if ((x & 1) == 0) {
        if (kx == 0) { x0 = 0; x1 = 0; wx0 = 1.f; wx1 = 0.f; }
        else { x0 = kx - 1; x1 = kx; wx0 = 0.25f; wx1 = 0.75f; }
    } else {
        if (kx == Wi - 1) { x0 = kx; x1 = kx; wx0 = 1.f; wx1 = 0.f; }
        else { x0 = kx; x1 = kx + 1; wx0 = 0.75f; wx1 = 0.25f; }
    }
    const float* base = in + (size_t)nc * Hi * Wi;
    float v = wy0 * (wx0 * base[(size_t)y0 * Wi + x0] + wx1 * base[(size_t)y0 * Wi + x1])
            + wy1 * (wx0 * base[(size_t)y1 * Wi + x0] + wx1 * base[(size_t)y1 * Wi + x1]);
    out[idx] = 2.0f * v;
}

// ---------------- build conv input: [ref(3) | warped(3) | flow(2)] for 6 batches ----------------
__global__ void k_build_in8(const float* __restrict__ pyr, const float* __restrict__ flow,
                            float* __restrict__ in8, int H, int W) {
    int idx = blockIdx.x * 256 + threadIdx.x;
    int total = NBATCH * H * W;
    if (idx >= total) return;
    int x = idx % W;
    int y = (idx / W) % H;
    int n = idx / (W * H);
    int ref_f = (n < 3) ? n : n - 2;
    int sup_f = (n < 3) ? n + 1 : n - 3;
    size_t hw = (size_t)H * W;
    float fx = flow[((size_t)n * 2 + 0) * hw + (size_t)y * W + x];
    float fy = flow[((size_t)n * 2 + 1) * hw + (size_t)y * W + x];
    float ry = (float)y + fy;
    float rx = (float)x + fx;
    ry = fminf(fmaxf(ry, 0.f), (float)(H - 1));
    rx = fminf(fmaxf(rx, 0.f), (float)(W - 1));
    float y0f = floorf(ry), x0f = floorf(rx);
    float wy = ry - y0f, wx = rx - x0f;
    int y0 = (int)y0f, x0 = (int)x0f;
    int y1 = min(y0 + 1, H - 1), x1 = min(x0 + 1, W - 1);
    const float* sup = pyr + (size_t)sup_f * 3 * hw;
    const float* ref = pyr + (size_t)ref_f * 3 * hw;
    float* o = in8 + (size_t)n * 8 * hw + (size_t)y * W + x;
    #pragma unroll
    for (int c = 0; c < 3; c++) {
        const float* sc = sup + (size_t)c * hw;
        float g00 = sc[(size_t)y0 * W + x0], g01 = sc[(size_t)y0 * W + x1];
        float g10 = sc[(size_t)y1 * W + x0], g11 = sc[(size_t)y1 * W + x1];
        float v = g00 * (1.f - wy) * (1.f - wx) + g01 * (1.f - wy) * wx
                + g10 * wy * (1.f - wx) + g11 * wy * wx;
        o[(size_t)(3 + c) * hw] = v;
        o[(size_t)c * hw] = ref[(size_t)c * hw + (size_t)y * W + x];
    }
    o[6 * hw] = fx;
    o[7 * hw] = fy;
}

// ================= unified direct 7x7 conv =================
// 32x32 tile. 256 threads: tq=tid&7 (4 consecutive x px), trow=tid>>3 (row).
// Input LDS: 38x38 halo, row stride 44 floats (rows & tq*4 16B-aligned; bank
// rotation 12/row -> uniform) -> ds_read_b128. Double-buffered, 1 barrier/ic.
// Weights in LDS per 8-ic chunk, ky-rows padded to 8 -> 2 broadcast b128/row.
// Accumulation order per output: ic asc, ky asc, kx asc (bitwise == prev rounds).

#define IW 38
#define ISTR 44
#define NI (IW * IW)          // 1444 valid elems
#define ISZ (IW * ISTR)       // 1672 (multiple of 4 -> both buffers 16B aligned)
#define NR 6                  // ceil(1444/256)

__device__ __forceinline__ void conv_iload(const float* __restrict__ ip, float* sreg,
        int tid, int by, int bx, int H, int W) {
    #pragma unroll
    for (int k = 0; k < NR; k++) {
        int tpos = tid + k * 256;
        int ly = tpos / IW;
        int lx = tpos - ly * IW;
        int gy = by + ly - 3, gx = bx + lx - 3;
        bool ok = (tpos < NI) && ((unsigned)gy < (unsigned)H) && ((unsigned)gx < (unsigned)W);
        sreg[k] = ok ? ip[gy * W + gx] : 0.f;
    }
}

__device__ __forceinline__ void conv_istore(float* __restrict__ dst, const float* sreg,
        int tid) {
    #pragma unroll
    for (int k = 0; k < NR; k++) {
        int tpos = tid + k * 256;
        int ly = tpos / IW;
        int lx = tpos - ly * IW;
        if (tpos < NI) dst[ly * ISTR + lx] = sreg[k];
    }
}

template<int OCB, int NWR>
__device__ __forceinline__ void conv_wload(const float* __restrict__ wt, float* wreg,
        int tid, int oc0, int IC, int cbase) {
    constexpr int NWELEM = OCB * 8 * 49;
    #pragma unroll
    for (int k = 0; k < NWR; k++) {
        int tpos = tid + k * 256;
        int oc = tpos / 392;            // 8*49
        int rem = tpos - oc * 392;
        int icc = rem / 49;
        int kk = rem - icc * 49;
        wreg[k] = (tpos < NWELEM) ? wt[((size_t)(oc0 + oc) * IC + (cbase + icc)) * 49 + kk] : 0.f;
    }
}

template<int OCB, bool RELU, bool ACC>
__global__ __launch_bounds__(256, 4) void k_conv(
        const float* __restrict__ in, const float* __restrict__ wt,
        const float* __restrict__ bias, float* __restrict__ out,
        int IC, int OC, int H, int W, int ntx, int nty, int nocg) {
    constexpr int NWELEM = OCB * 8 * 49;
    constexpr int NWR = (NWELEM + 255) / 256;
    __shared__ float smi[2 * ISZ];
    __shared__ float smw[8 * OCB * 7 * 8];   // [icc][oc][ky][8]

    // bijective XCD swizzle (m204), oc-group fastest within an XCD chunk
    int nwg = gridDim.x, wg = blockIdx.x;
    int q = nwg >> 3, r = nwg & 7;
    int xcd = wg & 7, pos = wg >> 3;
    int logical = ((xcd < r) ? xcd * (q + 1) : r * (q + 1) + (xcd - r) * q) + pos;
    int ocg = logical % nocg; int t2 = logical / nocg;
    int tx = t2 % ntx; t2 /= ntx;
    int ty = t2 % nty; int n = t2 / nty;
    int oc0 = ocg * OCB;
    int bx = tx * 32, by = ty * 32;
    int tid = threadIdx.x;
    int tq = tid & 7, trow = tid >> 3;
    int hw = H * W;

    float acc[OCB][4];
    #pragma unroll
    for (int o = 0; o < OCB; o++)
        #pragma unroll
        for (int p = 0; p < 4; p++) acc[o][p] = 0.f;

    const float* ip0 = in + (size_t)n * IC * hw;
    float sreg[NR];
    float wreg[NWR];

    // prologue: weight chunk 0 + input plane 0 staged, plane 1 prefetched
    conv_wload<OCB, NWR>(wt, wreg, tid, oc0, IC, 0);
    conv_iload(ip0, sreg, tid, by, bx, H, W);
    conv_istore(smi, sreg, tid);
    if (IC > 1) conv_iload(ip0 + hw, sreg, tid, by, bx, H, W);

    for (int ic = 0; ic < IC; ++ic) {
        int cur = ic & 1;
        if ((ic & 7) == 0) {
            // end-of-prev-iter barrier guarantees nobody still reads smw
            #pragma unroll
            for (int k = 0; k < NWR; k++) {
                int tpos = tid + k * 256;
                if (tpos < NWELEM) {
                    int oc = tpos / 392;
                    int rem = tpos - oc * 392;
                    int icc = rem / 49;
                    int kk = rem - icc * 49;
                    int ky = kk / 7, kx = kk - ky * 7;
                    smw[((icc * OCB + oc) * 7 + ky) * 8 + kx] = wreg[k];
                }
            }
            __syncthreads();   // weights (and, at ic=0, prologue input) visible
            if (ic + 8 < IC) conv_wload<OCB, NWR>(wt, wreg, tid, oc0, IC, ic + 8);
        }
        if (ic + 1 < IC) {
            conv_istore(smi + (cur ^ 1) * ISZ, sreg, tid);
            if (ic + 2 < IC)
                conv_iload(ip0 + (size_t)(ic + 2) * hw, sreg, tid, by, bx, H, W);
        }
        int icc = ic & 7;
        const float* smc = smi + cur * ISZ + trow * ISTR + tq * 4;
        #pragma unroll
        for (int ky = 0; ky < 7; ++ky) {
            float4 xa = *(const float4*)(smc + ky * ISTR);
            float4 xb = *(const float4*)(smc + ky * ISTR + 4);
            float2 xc = *(const float2*)(smc + ky * ISTR + 8);
            float xin[10] = {xa.x, xa.y, xa.z, xa.w, xb.x, xb.y, xb.z, xb.w, xc.x, xc.y};
            #pragma unroll
            for (int oc = 0; oc < OCB; ++oc) {
                const float4* wp = (const float4*)(smw + ((icc * OCB + oc) * 7 + ky) * 8);
                float4 wa = wp[0], wb = wp[1];
                float wv[7] = {wa.x, wa.y, wa.z, wa.w, wb.x, wb.y, wb.z};
                #pragma unroll
                for (int kx = 0; kx < 7; ++kx) {
                    #pragma unroll
                    for (int p = 0; p < 4; p++)
                        acc[oc][p] = fmaf(xin[kx + p], wv[kx], acc[oc][p]);
                }
            }
        }
        __syncthreads();
    }

    // epilogue
    int ox0 = bx + tq * 4;
    int oy = by + trow;
    if (oy < H) {
        #pragma unroll
        for (int oc = 0; oc < OCB; ++oc) {
            float bv = bias[oc0 + oc];
            float v[4];
            #pragma unroll
            for (int p = 0; p < 4; p++) {
                v[p] = acc[oc][p] + bv;
                if (RELU) v[p] = fmaxf(v[p], 0.f);
            }
            float* op = out + ((size_t)n * OC + oc0 + oc) * hw + (size_t)oy * W + ox0;
            if (ox0 + 3 < W) {
                if (ACC) {
                    float4 o4 = *(const float4*)op;
                    o4.x += v[0]; o4.y += v[1]; o4.z += v[2]; o4.w += v[3];
                    *(float4*)op = o4;
                } else {
                    *(float4*)op = make_float4(v[0], v[1], v[2], v[3]);
                }
            } else {
                #pragma unroll
                for (int p = 0; p < 4; p++)
                    if (ox0 + p < W) { if (ACC) op[p] += v[p]; else op[p] = v[p]; }
            }
        }
    }
}

// ---------------- patch match + stable top-10 ----------------
__global__ __launch_bounds__(64) void k_match(
        const float* __restrict__ vid, const float* __restrict__ flow,
        float* __restrict__ out) {
    int q = blockIdx.x;
    int j = q % 48; q /= 48;
    int i = q % 48; q /= 48;
    int t = q % 4;
    int dtIdx = q / 4;
    int lane = threadIdx.x;

    float fh = 0.f, fw = 0.f, dtf = 0.f;
    int tid = t;
    if (dtIdx == 1) {
        if (t < 3) {
            size_t base = (((size_t)t * 2) * 192 + i * 4) * 192 + j * 4;
            fw = flow[base];
            fh = flow[base + (size_t)192 * 192];
        }
        tid = min(t + 1, 3);
        dtf = 1.f;
    } else if (dtIdx == 2) {
        if (t > 0) {
            size_t base = (((size_t)(t + 2) * 2) * 192 + i * 4) * 192 + j * 4;
            fw = flow[base];
            fh = flow[base + (size_t)192 * 192];
        }
        tid = max(t - 1, 0);
        dtf = -1.f;
    }

    __shared__ int sy0[27], sy1[27], sx0[27], sx1[27];
    __shared__ float sfy[27], sfx[27], qp[27];
    if (lane < 27) {
        int wq = lane / 3, p = lane % 3;
        float ry = (((float)(i * 4) + fh) + (float)(wq - 4)) + (float)(p - 1);
        ry = fminf(fmaxf(ry, 0.f), 191.f);
        float y0f = floorf(ry);
        int y0 = (int)y0f;
        sy0[lane] = y0; sy1[lane] = min(y0 + 1, 191); sfy[lane] = ry - y0f;
        float rx = (((float)(j * 4) + fw) + (float)(wq - 4)) + (float)(p - 1);
        rx = fminf(fmaxf(rx, 0.f), 191.f);
        float x0f = floorf(rx);
        int x0 = (int)x0f;
        sx0[lane] = x0; sx1[lane] = min(x0 + 1, 191); sfx[lane] = rx - x0f;
        int c = lane / 9, pp = lane % 9, py = pp / 3, px = pp % 3;
        int yy = min(max(i * 4 + py - 1, 0), 191);
        int xx = min(max(j * 4 + px - 1, 0), 191);
        qp[lane] = vid[(((size_t)t * 3 + c) * 192 + yy) * 192 + xx];
    }
    __syncthreads();

    const float* frame = vid + (size_t)tid * 3 * 192 * 192;
    float dist[2];
    int widx[2];
    #pragma unroll
    for (int r = 0; r < 2; r++) {
        int w = lane + 64 * r;
        if (w < 81) {
            int wy = w / 9, wx = w % 9;
            float dsum = 0.f;
            for (int c = 0; c < 3; c++) {
                const float* fc = frame + (size_t)c * 36864;
                #pragma unroll
                for (int py = 0; py < 3; py++) {
                    int ye = wy * 3 + py;
                    int y0 = sy0[ye], y1 = sy1[ye];
                    float fy = sfy[ye];
                    const float* r0 = fc + (size_t)y0 * 192;
                    const float* r1 = fc + (size_t)y1 * 192;
                    #pragma unroll
                    for (int px = 0; px < 3; px++) {
                        int xe = wx * 3 + px;
                        int x0 = sx0[xe], x1 = sx1[xe];
                        float fx = sfx[xe];
                        float g00 = r0[x0], g01 = r0[x1], g10 = r1[x0], g11 = r1[x1];
                        float cand = g00 * (1.f - fy) * (1.f - fx) + g01 * (1.f - fy) * fx
                                   + g10 * fy * (1.f - fx) + g11 * fy * fx;
                        float diff = qp[(c * 3 + py) * 3 + px] - cand;
                        dsum = fmaf(diff, diff, dsum);
                    }
                }
            }
            dist[r] = dsum; widx[r] = w;
        } else {
            dist[r] = __builtin_inff(); widx[r] = 1000;
        }
    }

    for (int k = 0; k < 10; k++) {
        float d = dist[0]; int wi = widx[0];
        if (dist[1] < d || (dist[1] == d && widx[1] < wi)) { d = dist[1]; wi = widx[1]; }
        #pragma unroll
        for (int off = 32; off >= 1; off >>= 1) {
            float od = __shfl_xor(d, off);
            int ow = __shfl_xor(wi, off);
            if (od < d || (od == d && ow < wi)) { d = od; wi = ow; }
        }
        if (lane == 0) {
            size_t ob = ((((size_t)t * 48 + i) * 48 + j) * 30 + dtIdx * 10 + k) * 3;
            out[ob + 0] = dtf;
            out[ob + 1] = fh + (float)(wi / 9 - 4);
            out[ob + 2] = fw + (float)(wi % 9 - 4);
        }
        if (widx[0] == wi) dist[0] = __builtin_inff();
        if (widx[1] == wi) dist[1] = __builtin_inff();
    }
}

// ---------------- host ----------------
extern "C" void kernel_launch(void* const* d_in, const int* in_sizes, int n_in,
                              void* d_out, int out_size, void* d_ws, size_t ws_size,
                              hipStream_t stream) {
    const float* vid = (const float*)d_in[0];
    const float* w1 = (const float*)d_in[1];  const float* b1 = (const float*)d_in[2];
    const float* w2 = (const float*)d_in[3];  const float* b2 = (const float*)d_in[4];
    const float* w3 = (const float*)d_in[5];  const float* b3 = (const float*)d_in[6];
    const float* w4 = (const float*)d_in[7];  const float* b4 = (const float*)d_in[8];
    const float* w5 = (const float*)d_in[9];  const float* b5 = (const float*)d_in[10];
    float* out = (float*)d_out;
    float* ws = (float*)d_ws;

    float* nv    = ws;                    //   442368
    float* pyr1  = nv    + 442368;        //   110592
    float* pyr2  = pyr1  + 110592;        //    27648
    float* pyr3  = pyr2  + 27648;         //     6912
    float* flowA = pyr3  + 6912;          //   442368 (6,2,192,192)
    float* flowB = flowA + 442368;        //   442368
    float* in8   = flowB + 442368;        //  1769472 (6,8,192,192)
    float* bufA  = in8   + 1769472;       //  7077888 (6,32,192,192)
    float* bufB  = bufA  + 7077888;       // 14155776 (6,64,192,192)

    k_normalize<<<(442368 + 255) / 256, 256, 0, stream>>>(vid, nv);
    k_pool<<<(110592 + 255) / 256, 256, 0, stream>>>(nv, pyr1, 12, 96, 96);
    k_pool<<<(27648 + 255) / 256, 256, 0, stream>>>(pyr1, pyr2, 12, 48, 48);
    k_pool<<<(6912 + 255) / 256, 256, 0, stream>>>(pyr2, pyr3, 12, 24, 24);

    const float* pyrs[4] = {nv, pyr1, pyr2, pyr3};

    float* cur = flowA;
    float* oth = flowB;
    hipMemsetAsync(cur, 0, (size_t)NBATCH * 2 * 24 * 24 * 4, stream);
    for (int l = 3; l >= 0; --l) {
        int H = H0 >> l, W = W0 >> l;
        if (l < 3) {
            k_upsample2x<<<((12 * H * W) + 255) / 256, 256, 0, stream>>>(cur, oth, 12, H / 2, W / 2);
            float* tsw = cur; cur = oth; oth = tsw;
        }
        k_build_in8<<<((NBATCH * H * W) + 255) / 256, 256, 0, stream>>>(pyrs[l], cur, in8, H, W);

        const float* W1 = w1 + (size_t)l * 32 * 8 * 49;  const float* B1 = b1 + l * 32;
        const float* W2 = w2 + (size_t)l * 64 * 32 * 49; const float* B2 = b2 + l * 64;
        const float* W3 = w3 + (size_t)l * 32 * 64 * 49; const float* B3 = b3 + l * 32;
        const float* W4 = w4 + (size_t)l * 16 * 32 * 49; const float* B4 = b4 + l * 16;
        const float* W5 = w5 + (size_t)l * 2 * 16 * 49;  const float* B5 = b5 + l * 2;

        int nt = (H + 31) / 32;
        int ntt = nt * nt;
        k_conv<4, true,  false><<<ntt * 8 * 6, 256, 0, stream>>>(in8,  W1, B1, bufA, 8,  32, H, W, nt, nt, 8);
        k_conv<8, true,  false><<<ntt * 8 * 6, 256, 0, stream>>>(bufA, W2, B2, bufB, 32, 64, H, W, nt, nt, 8);
        k_conv<4, true,  false><<<ntt * 8 * 6, 256, 0, stream>>>(bufB, W3, B3, bufA, 64, 32, H, W, nt, nt, 8);
        k_conv<4, true,  false><<<ntt * 4 * 6, 256, 0, stream>>>(bufA, W4, B4, bufB, 32, 16, H, W, nt, nt, 4);
        k_conv<2, false, true ><<<ntt * 1 * 6, 256, 0, stream>>>(bufB, W5, B5, cur,  16, 2,  H, W, nt, nt, 1);
    }

    k_match<<<27648, 64, 0, stream>>>(vid, cur, out);
}

// Round 7
// 3329.369 us; speedup vs baseline: 1.6100x; 1.6100x over previous
//
#include <hip/hip_runtime.h>
#include <cstdint>

#define H0 192
#define W0 192
#define TT 4
#define NBATCH 6   // both spynet directions batched: n<3 -> fwd, n>=3 -> bwd

// ---------------- normalize ----------------
__global__ void k_normalize(const float* __restrict__ vid, float* __restrict__ nv) {
    int idx = blockIdx.x * 256 + threadIdx.x;
    const int total = TT * 3 * H0 * W0;
    if (idx >= total) return;
    int c = (idx / (H0 * W0)) % 3;
    float m = (c == 0) ? 0.485f : (c == 1) ? 0.456f : 0.406f;
    float s = (c == 0) ? 0.229f : (c == 1) ? 0.224f : 0.225f;
    nv[idx] = (vid[idx] - m) / s;
}

// ---------------- 2x2 average pool ----------------
__global__ void k_pool(const float* __restrict__ in, float* __restrict__ out,
                       int NC, int Ho, int Wo) {
    int idx = blockIdx.x * 256 + threadIdx.x;
    int total = NC * Ho * Wo;
    if (idx >= total) return;
    int x = idx % Wo;
    int y = (idx / Wo) % Ho;
    int nc = idx / (Wo * Ho);
    const float* p = in + ((size_t)nc * (Ho * 2) + y * 2) * (size_t)(Wo * 2) + x * 2;
    int Wi = Wo * 2;
    out[idx] = (p[0] + p[1] + p[Wi] + p[Wi + 1]) * 0.25f;
}

// ---------------- 2x bilinear upsample (jax.image.resize semantics), x2.0 scale ----------------
__global__ void k_upsample2x(const float* __restrict__ in, float* __restrict__ out,
                             int NC, int Hi, int Wi) {
    int Ho = Hi * 2, Wo = Wi * 2;
    int idx = blockIdx.x * 256 + threadIdx.x;
    int total = NC * Ho * Wo;
    if (idx >= total) return;
    int x = idx % Wo;
    int y = (idx / Wo) % Ho;
    int nc = idx / (Wo * Ho);
    int ky = y >> 1, kx = x >> 1;
    int y0, y1, x0, x1;
    float wy0, wy1, wx0, wx1;
    if ((y & 1) == 0) {
        if (ky == 0) { y0 = 0; y1 = 0; wy0 = 1.f; wy1 = 0.f; }
        else { y0 = ky - 1; y1 = ky; wy0 = 0.25f; wy1 = 0.75f; }
    } else {
        if (ky == Hi - 1) { y0 = ky; y1 = ky; wy0 = 1.f; wy1 = 0.f; }
        else { y0 = ky; y1 = ky + 1; wy0 = 0.75f; wy1 = 0.25f; }
    }
    if ((x & 1) == 0) {
        if (kx == 0) { x0 = 0; x1 = 0; wx0 = 1.f; wx1 = 0.f; }
        else { x0 = kx - 1; x1 = kx; wx0 = 0.25f; wx1 = 0.75f; }
    } else {
        if (kx == Wi - 1) { x0 = kx; x1 = kx; wx0 = 1.f; wx1 = 0.f; }
        else { x0 = kx; x1 = kx + 1; wx0 = 0.75f; wx1 = 0.25f; }
    }
    const float* base = in + (size_t)nc * Hi * Wi;
    float v = wy0 * (wx0 * base[(size_t)y0 * Wi + x0] + wx1 * base[(size_t)y0 * Wi + x1])
            + wy1 * (wx0 * base[(size_t)y1 * Wi + x0] + wx1 * base[(size_t)y1 * Wi + x1]);
    out[idx] = 2.0f * v;
}

// ---------------- build conv input: [ref(3) | warped(3) | flow(2)] for 6 batches ----------------
__global__ void k_build_in8(const float* __restrict__ pyr, const float* __restrict__ flow,
                            float* __restrict__ in8, int H, int W) {
    int idx = blockIdx.x * 256 + threadIdx.x;
    int total = NBATCH * H * W;
    if (idx >= total) return;
    int x = idx % W;
    int y = (idx / W) % H;
    int n = idx / (W * H);
    int ref_f = (n < 3) ? n : n - 2;
    int sup_f = (n < 3) ? n + 1 : n - 3;
    size_t hw = (size_t)H * W;
    float fx = flow[((size_t)n * 2 + 0) * hw + (size_t)y * W + x];
    float fy = flow[((size_t)n * 2 + 1) * hw + (size_t)y * W + x];
    float ry = (float)y + fy;
    float rx = (float)x + fx;
    ry = fminf(fmaxf(ry, 0.f), (float)(H - 1));
    rx = fminf(fmaxf(rx, 0.f), (float)(W - 1));
    float y0f = floorf(ry), x0f = floorf(rx);
    float wy = ry - y0f, wx = rx - x0f;
    int y0 = (int)y0f, x0 = (int)x0f;
    int y1 = min(y0 + 1, H - 1), x1 = min(x0 + 1, W - 1);
    const float* sup = pyr + (size_t)sup_f * 3 * hw;
    const float* ref = pyr + (size_t)ref_f * 3 * hw;
    float* o = in8 + (size_t)n * 8 * hw + (size_t)y * W + x;
    #pragma unroll
    for (int c = 0; c < 3; c++) {
        const float* sc = sup + (size_t)c * hw;
        float g00 = sc[(size_t)y0 * W + x0], g01 = sc[(size_t)y0 * W + x1];
        float g10 = sc[(size_t)y1 * W + x0], g11 = sc[(size_t)y1 * W + x1];
        float v = g00 * (1.f - wy) * (1.f - wx) + g01 * (1.f - wy) * wx
                + g10 * wy * (1.f - wx) + g11 * wy * wx;
        o[(size_t)(3 + c) * hw] = v;
        o[(size_t)c * hw] = ref[(size_t)c * hw + (size_t)y * W + x];
    }
    o[6 * hw] = fx;
    o[7 * hw] = fy;
}

// ================= unified direct 7x7 conv =================
// 32x32 tile. 256 threads: tq=tid&7 (4 consecutive x px), trow=tid>>3 (row).
// Input LDS: 38x38 halo, row stride 44 floats -> vector ds_read (b128).
// Double-buffered, 1 barrier/ic. Weights in LDS per 4-ic chunk (short wreg
// prefetch array = low register pressure), ky-rows padded to 8 -> broadcast b128.
// Accumulation order per output: ic asc, ky asc, kx asc (bitwise == prev rounds).
// NO launch_bounds min-waves: round-5's (256,4) forced a 64-VGPR cap -> 2GB of
// scratch spills (FETCH 1.7GB, WRITE 3GB per dispatch). Let natural ~100 VGPR ride.

#define IW 38
#define ISTR 44
#define NI (IW * IW)          // 1444 valid elems
#define ISZ (IW * ISTR)       // 1672 (multiple of 4 -> both buffers 16B aligned)
#define NR 6                  // ceil(1444/256)

__device__ __forceinline__ void conv_iload(const float* __restrict__ ip, float* sreg,
        int tid, int by, int bx, int H, int W) {
    #pragma unroll
    for (int k = 0; k < NR; k++) {
        int tpos = tid + k * 256;
        int ly = tpos / IW;
        int lx = tpos - ly * IW;
        int gy = by + ly - 3, gx = bx + lx - 3;
        bool ok = (tpos < NI) && ((unsigned)gy < (unsigned)H) && ((unsigned)gx < (unsigned)W);
        sreg[k] = ok ? ip[gy * W + gx] : 0.f;
    }
}

__device__ __forceinline__ void conv_istore(float* __restrict__ dst, const float* sreg,
        int tid) {
    #pragma unroll
    for (int k = 0; k < NR; k++) {
        int tpos = tid + k * 256;
        int ly = tpos / IW;
        int lx = tpos - ly * IW;
        if (tpos < NI) dst[ly * ISTR + lx] = sreg[k];
    }
}

// weights: 4-ic chunk, NWELEM = OCB*4*49
template<int OCB, int NWR>
__device__ __forceinline__ void conv_wload(const float* __restrict__ wt, float* wreg,
        int tid, int oc0, int IC, int cbase) {
    constexpr int NWELEM = OCB * 4 * 49;
    #pragma unroll
    for (int k = 0; k < NWR; k++) {
        int tpos = tid + k * 256;
        int oc = tpos / 196;            // 4*49
        int rem = tpos - oc * 196;
        int icc = rem / 49;
        int kk = rem - icc * 49;
        wreg[k] = (tpos < NWELEM) ? wt[((size_t)(oc0 + oc) * IC + (cbase + icc)) * 49 + kk] : 0.f;
    }
}

template<int OCB, bool RELU, bool ACC>
__global__ __launch_bounds__(256) void k_conv(
        const float* __restrict__ in, const float* __restrict__ wt,
        const float* __restrict__ bias, float* __restrict__ out,
        int IC, int OC, int H, int W, int ntx, int nty, int nocg) {
    constexpr int NWELEM = OCB * 4 * 49;
    constexpr int NWR = (NWELEM + 255) / 256;
    __shared__ float smi[2 * ISZ];
    __shared__ float smw[4 * OCB * 7 * 8];   // [icc][oc][ky][8]

    // bijective XCD swizzle (m204), oc-group fastest within an XCD chunk
    int nwg = gridDim.x, wg = blockIdx.x;
    int q = nwg >> 3, r = nwg & 7;
    int xcd = wg & 7, pos = wg >> 3;
    int logical = ((xcd < r) ? xcd * (q + 1) : r * (q + 1) + (xcd - r) * q) + pos;
    int ocg = logical % nocg; int t2 = logical / nocg;
    int tx = t2 % ntx; t2 /= ntx;
    int ty = t2 % nty; int n = t2 / nty;
    int oc0 = ocg * OCB;
    int bx = tx * 32, by = ty * 32;
    int tid = threadIdx.x;
    int tq = tid & 7, trow = tid >> 3;
    int hw = H * W;

    float acc[OCB][4];
    #pragma unroll
    for (int o = 0; o < OCB; o++)
        #pragma unroll
        for (int p = 0; p < 4; p++) acc[o][p] = 0.f;

    const float* ip0 = in + (size_t)n * IC * hw;
    float sreg[NR];
    float wreg[NWR];

    // prologue: weight chunk 0 + input plane 0 staged, plane 1 prefetched
    conv_wload<OCB, NWR>(wt, wreg, tid, oc0, IC, 0);
    conv_iload(ip0, sreg, tid, by, bx, H, W);
    conv_istore(smi, sreg, tid);
    if (IC > 1) conv_iload(ip0 + hw, sreg, tid, by, bx, H, W);

    for (int ic = 0; ic < IC; ++ic) {
        int cur = ic & 1;
        if ((ic & 3) == 0) {
            // end-of-prev-iter barrier guarantees nobody still reads smw
            #pragma unroll
            for (int k = 0; k < NWR; k++) {
                int tpos = tid + k * 256;
                if (tpos < NWELEM) {
                    int oc = tpos / 196;
                    int rem = tpos - oc * 196;
                    int icc = rem / 49;
                    int kk = rem - icc * 49;
                    int ky = kk / 7, kx = kk - ky * 7;
                    smw[((icc * OCB + oc) * 7 + ky) * 8 + kx] = wreg[k];
                }
            }
            __syncthreads();   // weights (and, at ic=0, prologue input) visible
            if (ic + 4 < IC) conv_wload<OCB, NWR>(wt, wreg, tid, oc0, IC, ic + 4);
        }
        if (ic + 1 < IC) {
            conv_istore(smi + (cur ^ 1) * ISZ, sreg, tid);
            if (ic + 2 < IC)
                conv_iload(ip0 + (size_t)(ic + 2) * hw, sreg, tid, by, bx, H, W);
        }
        int icc = ic & 3;
        const float* smc = smi + cur * ISZ + trow * ISTR + tq * 4;
        #pragma unroll
        for (int ky = 0; ky < 7; ++ky) {
            float4 xa = *(const float4*)(smc + ky * ISTR);
            float4 xb = *(const float4*)(smc + ky * ISTR + 4);
            float2 xc = *(const float2*)(smc + ky * ISTR + 8);
            float xin[10] = {xa.x, xa.y, xa.z, xa.w, xb.x, xb.y, xb.z, xb.w, xc.x, xc.y};
            #pragma unroll
            for (int oc = 0; oc < OCB; ++oc) {
                const float4* wp = (const float4*)(smw + ((icc * OCB + oc) * 7 + ky) * 8);
                float4 wa = wp[0], wb = wp[1];
                float wv[7] = {wa.x, wa.y, wa.z, wa.w, wb.x, wb.y, wb.z};
                #pragma unroll
                for (int kx = 0; kx < 7; ++kx) {
                    #pragma unroll
                    for (int p = 0; p < 4; p++)
                        acc[oc][p] = fmaf(xin[kx + p], wv[kx], acc[oc][p]);
                }
            }
        }
        __syncthreads();
    }

    // epilogue
    int ox0 = bx + tq * 4;
    int oy = by + trow;
    if (oy < H) {
        #pragma unroll
        for (int oc = 0; oc < OCB; ++oc) {
            float bv = bias[oc0 + oc];
            float v[4];
            #pragma unroll
            for (int p = 0; p < 4; p++) {
                v[p] = acc[oc][p] + bv;
                if (RELU) v[p] = fmaxf(v[p], 0.f);
            }
            float* op = out + ((size_t)n * OC + oc0 + oc) * hw + (size_t)oy * W + ox0;
            if (ox0 + 3 < W) {
                if (ACC) {
                    float4 o4 = *(const float4*)op;
                    o4.x += v[0]; o4.y += v[1]; o4.z += v[2]; o4.w += v[3];
                    *(float4*)op = o4;
                } else {
                    *(float4*)op = make_float4(v[0], v[1], v[2], v[3]);
                }
            } else {
                #pragma unroll
                for (int p = 0; p < 4; p++)
                    if (ox0 + p < W) { if (ACC) op[p] += v[p]; else op[p] = v[p]; }
            }
        }
    }
}

// ---------------- patch match + stable top-10 ----------------
__global__ __launch_bounds__(64) void k_match(
        const float* __restrict__ vid, const float* __restrict__ flow,
        float* __restrict__ out) {
    int q = blockIdx.x;
    int j = q % 48; q /= 48;
    int i = q % 48; q /= 48;
    int t = q % 4;
    int dtIdx = q / 4;
    int lane = threadIdx.x;

    float fh = 0.f, fw = 0.f, dtf = 0.f;
    int tid = t;
    if (dtIdx == 1) {
        if (t < 3) {
            size_t base = (((size_t)t * 2) * 192 + i * 4) * 192 + j * 4;
            fw = flow[base];
            fh = flow[base + (size_t)192 * 192];
        }
        tid = min(t + 1, 3);
        dtf = 1.f;
    } else if (dtIdx == 2) {
        if (t > 0) {
            size_t base = (((size_t)(t + 2) * 2) * 192 + i * 4) * 192 + j * 4;
            fw = flow[base];
            fh = flow[base + (size_t)192 * 192];
        }
        tid = max(t - 1, 0);
        dtf = -1.f;
    }

    __shared__ int sy0[27], sy1[27], sx0[27], sx1[27];
    __shared__ float sfy[27], sfx[27], qp[27];
    if (lane < 27) {
        int wq = lane / 3, p = lane % 3;
        float ry = (((float)(i * 4) + fh) + (float)(wq - 4)) + (float)(p - 1);
        ry = fminf(fmaxf(ry, 0.f), 191.f);
        float y0f = floorf(ry);
        int y0 = (int)y0f;
        sy0[lane] = y0; sy1[lane] = min(y0 + 1, 191); sfy[lane] = ry - y0f;
        float rx = (((float)(j * 4) + fw) + (float)(wq - 4)) + (float)(p - 1);
        rx = fminf(fmaxf(rx, 0.f), 191.f);
        float x0f = floorf(rx);
        int x0 = (int)x0f;
        sx0[lane] = x0; sx1[lane] = min(x0 + 1, 191); sfx[lane] = rx - x0f;
        int c = lane / 9, pp = lane % 9, py = pp / 3, px = pp % 3;
        int yy = min(max(i * 4 + py - 1, 0), 191);
        int xx = min(max(j * 4 + px - 1, 0), 191);
        qp[lane] = vid[(((size_t)t * 3 + c) * 192 + yy) * 192 + xx];
    }
    __syncthreads();

    const float* frame = vid + (size_t)tid * 3 * 192 * 192;
    float dist[2];
    int widx[2];
    #pragma unroll
    for (int r = 0; r < 2; r++) {
        int w = lane + 64 * r;
        if (w < 81) {
            int wy = w / 9, wx = w % 9;
            float dsum = 0.f;
            for (int c = 0; c < 3; c++) {
                const float* fc = frame + (size_t)c * 36864;
                #pragma unroll
                for (int py = 0; py < 3; py++) {
                    int ye = wy * 3 + py;
                    int y0 = sy0[ye], y1 = sy1[ye];
                    float fy = sfy[ye];
                    const float* r0 = fc + (size_t)y0 * 192;
                    const float* r1 = fc + (size_t)y1 * 192;
                    #pragma unroll
                    for (int px = 0; px < 3; px++) {
                        int xe = wx * 3 + px;
                        int x0 = sx0[xe], x1 = sx1[xe];
                        float fx = sfx[xe];
                        float g00 = r0[x0], g01 = r0[x1], g10 = r1[x0], g11 = r1[x1];
                        float cand = g00 * (1.f - fy) * (1.f - fx) + g01 * (1.f - fy) * fx
                                   + g10 * fy * (1.f - fx) + g11 * fy * fx;
                        float diff = qp[(c * 3 + py) * 3 + px] - cand;
                        dsum = fmaf(diff, diff, dsum);
                    }
                }
            }
            dist[r] = dsum; widx[r] = w;
        } else {
            dist[r] = __builtin_inff(); widx[r] = 1000;
        }
    }

    for (int k = 0; k < 10; k++) {
        float d = dist[0]; int wi = widx[0];
        if (dist[1] < d || (dist[1] == d && widx[1] < wi)) { d = dist[1]; wi = widx[1]; }
        #pragma unroll
        for (int off = 32; off >= 1; off >>= 1) {
            float od = __shfl_xor(d, off);
            int ow = __shfl_xor(wi, off);
            if (od < d || (od == d && ow < wi)) { d = od; wi = ow; }
        }
        if (lane == 0) {
            size_t ob = ((((size_t)t * 48 + i) * 48 + j) * 30 + dtIdx * 10 + k) * 3;
            out[ob + 0] = dtf;
            out[ob + 1] = fh + (float)(wi / 9 - 4);
            out[ob + 2] = fw + (float)(wi % 9 - 4);
        }
        if (widx[0] == wi) dist[0] = __builtin_inff();
        if (widx[1] == wi) dist[1] = __builtin_inff();
    }
}

// ---------------- host ----------------
extern "C" void kernel_launch(void* const* d_in, const int* in_sizes, int n_in,
                              void* d_out, int out_size, void* d_ws, size_t ws_size,
                              hipStream_t stream) {
    const float* vid = (const float*)d_in[0];
    const float* w1 = (const float*)d_in[1];  const float* b1 = (const float*)d_in[2];
    const float* w2 = (const float*)d_in[3];  const float* b2 = (const float*)d_in[4];
    const float* w3 = (const float*)d_in[5];  const float* b3 = (const float*)d_in[6];
    const float* w4 = (const float*)d_in[7];  const float* b4 = (const float*)d_in[8];
    const float* w5 = (const float*)d_in[9];  const float* b5 = (const float*)d_in[10];
    float* out = (float*)d_out;
    float* ws = (float*)d_ws;

    float* nv    = ws;                    //   442368
    float* pyr1  = nv    + 442368;        //   110592
    float* pyr2  = pyr1  + 110592;        //    27648
    float* pyr3  = pyr2  + 27648;         //     6912
    float* flowA = pyr3  + 6912;          //   442368 (6,2,192,192)
    float* flowB = flowA + 442368;        //   442368
    float* in8   = flowB + 442368;        //  1769472 (6,8,192,192)
    float* bufA  = in8   + 1769472;       //  7077888 (6,32,192,192)
    float* bufB  = bufA  + 7077888;       // 14155776 (6,64,192,192)

    k_normalize<<<(442368 + 255) / 256, 256, 0, stream>>>(vid, nv);
    k_pool<<<(110592 + 255) / 256, 256, 0, stream>>>(nv, pyr1, 12, 96, 96);
    k_pool<<<(27648 + 255) / 256, 256, 0, stream>>>(pyr1, pyr2, 12, 48, 48);
    k_pool<<<(6912 + 255) / 256, 256, 0, stream>>>(pyr2, pyr3, 12, 24, 24);

    const float* pyrs[4] = {nv, pyr1, pyr2, pyr3};

    float* cur = flowA;
    float* oth = flowB;
    hipMemsetAsync(cur, 0, (size_t)NBATCH * 2 * 24 * 24 * 4, stream);
    for (int l = 3; l >= 0; --l) {
        int H = H0 >> l, W = W0 >> l;
        if (l < 3) {
            k_upsample2x<<<((12 * H * W) + 255) / 256, 256, 0, stream>>>(cur, oth, 12, H / 2, W / 2);
            float* tsw = cur; cur = oth; oth = tsw;
        }
        k_build_in8<<<((NBATCH * H * W) + 255) / 256, 256, 0, stream>>>(pyrs[l], cur, in8, H, W);

        const float* W1 = w1 + (size_t)l * 32 * 8 * 49;  const float* B1 = b1 + l * 32;
        const float* W2 = w2 + (size_t)l * 64 * 32 * 49; const float* B2 = b2 + l * 64;
        const float* W3 = w3 + (size_t)l * 32 * 64 * 49; const float* B3 = b3 + l * 32;
        const float* W4 = w4 + (size_t)l * 16 * 32 * 49; const float* B4 = b4 + l * 16;
        const float* W5 = w5 + (size_t)l * 2 * 16 * 49;  const float* B5 = b5 + l * 2;

        int nt = (H + 31) / 32;
        int ntt = nt * nt;
        k_conv<4, true,  false><<<ntt * 8 * 6, 256, 0, stream>>>(in8,  W1, B1, bufA, 8,  32, H, W, nt, nt, 8);
        k_conv<8, true,  false><<<ntt * 8 * 6, 256, 0, stream>>>(bufA, W2, B2, bufB, 32, 64, H, W, nt, nt, 8);
        k_conv<8, true,  false><<<ntt * 4 * 6, 256, 0, stream>>>(bufB, W3, B3, bufA, 64, 32, H, W, nt, nt, 4);
        k_conv<4, true,  false><<<ntt * 4 * 6, 256, 0, stream>>>(bufA, W4, B4, bufB, 32, 16, H, W, nt, nt, 4);
        k_conv<2, false, true ><<<ntt * 1 * 6, 256, 0, stream>>>(bufB, W5, B5, cur,  16, 2,  H, W, nt, nt, 1);
    }

    k_match<<<27648, 64, 0, stream>>>(vid, cur, out);
}

// Round 9
// 3261.340 us; speedup vs baseline: 1.6436x; 1.0209x over previous
//
#include <hip/hip_runtime.h>
#include <cstdint>

#define H0 192
#define W0 192
#define TT 4
#define NBATCH 6   // both spynet directions batched: n<3 -> fwd, n>=3 -> bwd

// ---------------- normalize ----------------
__global__ void k_normalize(const float* __restrict__ vid, float* __restrict__ nv) {
    int idx = blockIdx.x * 256 + threadIdx.x;
    const int total = TT * 3 * H0 * W0;
    if (idx >= total) return;
    int c = (idx / (H0 * W0)) % 3;
    float m = (c == 0) ? 0.485f : (c == 1) ? 0.456f : 0.406f;
    float s = (c == 0) ? 0.229f : (c == 1) ? 0.224f : 0.225f;
    nv[idx] = (vid[idx] - m) / s;
}

// ---------------- 2x2 average pool ----------------
__global__ void k_pool(const float* __restrict__ in, float* __restrict__ out,
                       int NC, int Ho, int Wo) {
    int idx = blockIdx.x * 256 + threadIdx.x;
    int total = NC * Ho * Wo;
    if (idx >= total) return;
    int x = idx % Wo;
    int y = (idx / Wo) % Ho;
    int nc = idx / (Wo * Ho);
    const float* p = in + ((size_t)nc * (Ho * 2) + y * 2) * (size_t)(Wo * 2) + x * 2;
    int Wi = Wo * 2;
    out[idx] = (p[0] + p[1] + p[Wi] + p[Wi + 1]) * 0.25f;
}

// ---------------- 2x bilinear upsample (jax.image.resize semantics), x2.0 scale ----------------
__global__ void k_upsample2x(const float* __restrict__ in, float* __restrict__ out,
                             int NC, int Hi, int Wi) {
    int Ho = Hi * 2, Wo = Wi * 2;
    int idx = blockIdx.x * 256 + threadIdx.x;
    int total = NC * Ho * Wo;
    if (idx >= total) return;
    int x = idx % Wo;
    int y = (idx / Wo) % Ho;
    int nc = idx / (Wo * Ho);
    int ky = y >> 1, kx = x >> 1;
    int y0, y1, x0, x1;
    float wy0, wy1, wx0, wx1;
    if ((y & 1) == 0) {
        if (ky == 0) { y0 = 0; y1 = 0; wy0 = 1.f; wy1 = 0.f; }
        else { y0 = ky - 1; y1 = ky; wy0 = 0.25f; wy1 = 0.75f; }
    } else {
        if (ky == Hi - 1) { y0 = ky; y1 = ky; wy0 = 1.f; wy1 = 0.f; }
        else { y0 = ky; y1 = ky + 1; wy0 = 0.75f; wy1 = 0.25f; }
    }
    if ((x & 1) == 0) {
        if (kx == 0) { x0 = 0; x1 = 0; wx0 = 1.f; wx1 = 0.f; }
        else { x0 = kx - 1; x1 = kx; wx0 = 0.25f; wx1 = 0.75f; }
    } else {
        if (kx == Wi - 1) { x0 = kx; x1 = kx; wx0 = 1.f; wx1 = 0.f; }
        else { x0 = kx; x1 = kx + 1; wx0 = 0.75f; wx1 = 0.25f; }
    }
    const float* base = in + (size_t)nc * Hi * Wi;
    float v = wy0 * (wx0 * base[(size_t)y0 * Wi + x0] + wx1 * base[(size_t)y0 * Wi + x1])
            + wy1 * (wx0 * base[(size_t)y1 * Wi + x0] + wx1 * base[(size_t)y1 * Wi + x1]);
    out[idx] = 2.0f * v;
}

// ---------------- build conv input: [ref(3) | warped(3) | flow(2)] for 6 batches ----------------
__global__ void k_build_in8(const float* __restrict__ pyr, const float* __restrict__ flow,
                            float* __restrict__ in8, int H, int W) {
    int idx = blockIdx.x * 256 + threadIdx.x;
    int total = NBATCH * H * W;
    if (idx >= total) return;
    int x = idx % W;
    int y = (idx / W) % H;
    int n = idx / (W * H);
    int ref_f = (n < 3) ? n : n - 2;
    int sup_f = (n < 3) ? n + 1 : n - 3;
    size_t hw = (size_t)H * W;
    float fx = flow[((size_t)n * 2 + 0) * hw + (size_t)y * W + x];
    float fy = flow[((size_t)n * 2 + 1) * hw + (size_t)y * W + x];
    float ry = (float)y + fy;
    float rx = (float)x + fx;
    ry = fminf(fmaxf(ry, 0.f), (float)(H - 1));
    rx = fminf(fmaxf(rx, 0.f), (float)(W - 1));
    float y0f = floorf(ry), x0f = floorf(rx);
    float wy = ry - y0f, wx = rx - x0f;
    int y0 = (int)y0f, x0 = (int)x0f;
    int y1 = min(y0 + 1, H - 1), x1 = min(x0 + 1, W - 1);
    const float* sup = pyr + (size_t)sup_f * 3 * hw;
    const float* ref = pyr + (size_t)ref_f * 3 * hw;
    float* o = in8 + (size_t)n * 8 * hw + (size_t)y * W + x;
    #pragma unroll
    for (int c = 0; c < 3; c++) {
        const float* sc = sup + (size_t)c * hw;
        float g00 = sc[(size_t)y0 * W + x0], g01 = sc[(size_t)y0 * W + x1];
        float g10 = sc[(size_t)y1 * W + x0], g11 = sc[(size_t)y1 * W + x1];
        float v = g00 * (1.f - wy) * (1.f - wx) + g01 * (1.f - wy) * wx
                + g10 * wy * (1.f - wx) + g11 * wy * wx;
        o[(size_t)(3 + c) * hw] = v;
        o[(size_t)c * hw] = ref[(size_t)c * hw + (size_t)y * W + x];
    }
    o[6 * hw] = fx;
    o[7 * hw] = fy;
}

// ================= unified direct 7x7 conv =================
// 32x32 tile. 256 threads: tq=tid&7 (4 consecutive x px), trow=tid>>3 (row).
// Input: LDS 38x38 halo @ stride 44 (b128 reads), double-buffered, 1 barrier/ic.
// Weights: NOT in LDS. Wave-uniform global loads -> compiler emits s_load into
// SGPRs; FMA reads the SGPR operand directly. One-ky-ahead prefetch (wl/wn,
// fully unrolled -> SSA) hides SMEM latency under 112 FMA instrs.
// WHY: r7 measured LDS-pipe saturation: 112 weight ds_read_b128/ic/wave =
// ~1350 LDS cyc vs 3136 FMA cyc, LDS shared CU-wide -> 50% VALUBusy ceiling.
// OCB=4 keeps live weight SGPRs at 2*28=56 (budget 102).
// Accumulation order per output: ic asc, ky asc, kx asc (bitwise == prev rounds).

#define IW 38
#define ISTR 44
#define NI (IW * IW)          // 1444 valid elems
#define ISZ (IW * ISTR)       // 1672 (multiple of 4 -> both buffers 16B aligned)
#define NR 6                  // ceil(1444/256)

__device__ __forceinline__ void conv_iload(const float* __restrict__ ip, float* sreg,
        int tid, int by, int bx, int H, int W) {
    #pragma unroll
    for (int k = 0; k < NR; k++) {
        int tpos = tid + k * 256;
        int ly = tpos / IW;
        int lx = tpos - ly * IW;
        int gy = by + ly - 3, gx = bx + lx - 3;
        bool ok = (tpos < NI) && ((unsigned)gy < (unsigned)H) && ((unsigned)gx < (unsigned)W);
        sreg[k] = ok ? ip[gy * W + gx] : 0.f;
    }
}

__device__ __forceinline__ void conv_istore(float* __restrict__ dst, const float* sreg,
        int tid) {
    #pragma unroll
    for (int k = 0; k < NR; k++) {
        int tpos = tid + k * 256;
        int ly = tpos / IW;
        int lx = tpos - ly * IW;
        if (tpos < NI) dst[ly * ISTR + lx] = sreg[k];
    }
}

template<int OCB, bool RELU, bool ACC>
__global__ __launch_bounds__(256) void k_conv(
        const float* __restrict__ in, const float* __restrict__ wt,
        const float* __restrict__ bias, float* __restrict__ out,
        int IC, int OC, int H, int W, int ntx, int nty, int nocg) {
    __shared__ float smi[2 * ISZ];

    // bijective XCD swizzle (m204), oc-group fastest within an XCD chunk
    int nwg = gridDim.x, wg = blockIdx.x;
    int q = nwg >> 3, r = nwg & 7;
    int xcd = wg & 7, pos = wg >> 3;
    int logical = ((xcd < r) ? xcd * (q + 1) : r * (q + 1) + (xcd - r) * q) + pos;
    int ocg = logical % nocg; int t2 = logical / nocg;
    int tx = t2 % ntx; t2 /= ntx;
    int ty = t2 % nty; int n = t2 / nty;
    int oc0 = ocg * OCB;
    int bx = tx * 32, by = ty * 32;
    int tid = threadIdx.x;
    int tq = tid & 7, trow = tid >> 3;
    int hw = H * W;

    float acc[OCB][4];
    #pragma unroll
    for (int o = 0; o < OCB; o++)
        #pragma unroll
        for (int p = 0; p < 4; p++) acc[o][p] = 0.f;

    const float* ip0 = in + (size_t)n * IC * hw;
    float sreg[NR];

    // prologue: input plane 0 staged, plane 1 prefetched; weights (ic0,ky0) preloaded
    conv_iload(ip0, sreg, tid, by, bx, H, W);
    conv_istore(smi, sreg, tid);
    if (IC > 1) conv_iload(ip0 + hw, sreg, tid, by, bx, H, W);

    float wl[OCB][7];
    #pragma unroll
    for (int oc = 0; oc < OCB; ++oc) {
        const float* wp = wt + ((size_t)(oc0 + oc) * IC) * 49;   // ic=0, ky=0
        #pragma unroll
        for (int kk = 0; kk < 7; ++kk) wl[oc][kk] = wp[kk];
    }
    __syncthreads();

    for (int ic = 0; ic < IC; ++ic) {
        int cur = ic & 1;
        if (ic + 1 < IC) {
            conv_istore(smi + (cur ^ 1) * ISZ, sreg, tid);
            if (ic + 2 < IC)
                conv_iload(ip0 + (size_t)(ic + 2) * hw, sreg, tid, by, bx, H, W);
        }
        const float* smc = smi + cur * ISZ + trow * ISTR + tq * 4;
        #pragma unroll
        for (int ky = 0; ky < 7; ++ky) {
            // prefetch next weight row (wave-uniform -> s_load into SGPRs)
            float wn[OCB][7];
            int nic = (ky == 6) ? ((ic + 1 < IC) ? ic + 1 : ic) : ic;
            int nky = (ky == 6) ? 0 : ky + 1;
            #pragma unroll
            for (int oc = 0; oc < OCB; ++oc) {
                const float* wp = wt + ((size_t)(oc0 + oc) * IC + nic) * 49 + nky * 7;
                #pragma unroll
                for (int kk = 0; kk < 7; ++kk) wn[oc][kk] = wp[kk];
            }
            float4 xa = *(const float4*)(smc + ky * ISTR);
            float4 xb = *(const float4*)(smc + ky * ISTR + 4);
            float2 xc = *(const float2*)(smc + ky * ISTR + 8);
            float xin[10] = {xa.x, xa.y, xa.z, xa.w, xb.x, xb.y, xb.z, xb.w, xc.x, xc.y};
            #pragma unroll
            for (int oc = 0; oc < OCB; ++oc) {
                #pragma unroll
                for (int kx = 0; kx < 7; ++kx) {
                    float wv = wl[oc][kx];
                    #pragma unroll
                    for (int p = 0; p < 4; p++)
                        acc[oc][p] = fmaf(xin[kx + p], wv, acc[oc][p]);
                }
            }
            #pragma unroll
            for (int oc = 0; oc < OCB; ++oc)
                #pragma unroll
                for (int kk = 0; kk < 7; ++kk) wl[oc][kk] = wn[oc][kk];
        }
        __syncthreads();
    }

    // epilogue
    int ox0 = bx + tq * 4;
    int oy = by + trow;
    if (oy < H) {
        #pragma unroll
        for (int oc = 0; oc < OCB; ++oc) {
            float bv = bias[oc0 + oc];
            float v[4];
            #pragma unroll
            for (int p = 0; p < 4; p++) {
                v[p] = acc[oc][p] + bv;
                if (RELU) v[p] = fmaxf(v[p], 0.f);
            }
            float* op = out + ((size_t)n * OC + oc0 + oc) * hw + (size_t)oy * W + ox0;
            if (ox0 + 3 < W) {
                if (ACC) {
                    float4 o4 = *(const float4*)op;
                    o4.x += v[0]; o4.y += v[1]; o4.z += v[2]; o4.w += v[3];
                    *(float4*)op = o4;
                } else {
                    *(float4*)op = make_float4(v[0], v[1], v[2], v[3]);
                }
            } else {
                #pragma unroll
                for (int p = 0; p < 4; p++)
                    if (ox0 + p < W) { if (ACC) op[p] += v[p]; else op[p] = v[p]; }
            }
        }
    }
}

// ---------------- patch match + stable top-10 ----------------
__global__ __launch_bounds__(64) void k_match(
        const float* __restrict__ vid, const float* __restrict__ flow,
        float* __restrict__ out) {
    int q = blockIdx.x;
    int j = q % 48; q /= 48;
    int i = q % 48; q /= 48;
    int t = q % 4;
    int dtIdx = q / 4;
    int lane = threadIdx.x;

    float fh = 0.f, fw = 0.f, dtf = 0.f;
    int tid = t;
    if (dtIdx == 1) {
        if (t < 3) {
            size_t base = (((size_t)t * 2) * 192 + i * 4) * 192 + j * 4;
            fw = flow[base];
            fh = flow[base + (size_t)192 * 192];
        }
        tid = min(t + 1, 3);
        dtf = 1.f;
    } else if (dtIdx == 2) {
        if (t > 0) {
            size_t base = (((size_t)(t + 2) * 2) * 192 + i * 4) * 192 + j * 4;
            fw = flow[base];
            fh = flow[base + (size_t)192 * 192];
        }
        tid = max(t - 1, 0);
        dtf = -1.f;
    }

    __shared__ int sy0[27], sy1[27], sx0[27], sx1[27];
    __shared__ float sfy[27], sfx[27], qp[27];
    if (lane < 27) {
        int wq = lane / 3, p = lane % 3;
        float ry = (((float)(i * 4) + fh) + (float)(wq - 4)) + (float)(p - 1);
        ry = fminf(fmaxf(ry, 0.f), 191.f);
        float y0f = floorf(ry);
        int y0 = (int)y0f;
        sy0[lane] = y0; sy1[lane] = min(y0 + 1, 191); sfy[lane] = ry - y0f;
        float rx = (((float)(j * 4) + fw) + (float)(wq - 4)) + (float)(p - 1);
        rx = fminf(fmaxf(rx, 0.f), 191.f);
        float x0f = floorf(rx);
        int x0 = (int)x0f;
        sx0[lane] = x0; sx1[lane] = min(x0 + 1, 191); sfx[lane] = rx - x0f;
        int c = lane / 9, pp = lane % 9, py = pp / 3, px = pp % 3;
        int yy = min(max(i * 4 + py - 1, 0), 191);
        int xx = min(max(j * 4 + px - 1, 0), 191);
        qp[lane] = vid[(((size_t)t * 3 + c) * 192 + yy) * 192 + xx];
    }
    __syncthreads();

    const float* frame = vid + (size_t)tid * 3 * 192 * 192;
    float dist[2];
    int widx[2];
    #pragma unroll
    for (int r = 0; r < 2; r++) {
        int w = lane + 64 * r;
        if (w < 81) {
            int wy = w / 9, wx = w % 9;
            float dsum = 0.f;
            for (int c = 0; c < 3; c++) {
                const float* fc = frame + (size_t)c * 36864;
                #pragma unroll
                for (int py = 0; py < 3; py++) {
                    int ye = wy * 3 + py;
                    int y0 = sy0[ye], y1 = sy1[ye];
                    float fy = sfy[ye];
                    const float* r0 = fc + (size_t)y0 * 192;
                    const float* r1 = fc + (size_t)y1 * 192;
                    #pragma unroll
                    for (int px = 0; px < 3; px++) {
                        int xe = wx * 3 + px;
                        int x0 = sx0[xe], x1 = sx1[xe];
                        float fx = sfx[xe];
                        float g00 = r0[x0], g01 = r0[x1], g10 = r1[x0], g11 = r1[x1];
                        float cand = g00 * (1.f - fy) * (1.f - fx) + g01 * (1.f - fy) * fx
                                   + g10 * fy * (1.f - fx) + g11 * fy * fx;
                        float diff = qp[(c * 3 + py) * 3 + px] - cand;
                        dsum = fmaf(diff, diff, dsum);
                    }
                }
            }
            dist[r] = dsum; widx[r] = w;
        } else {
            dist[r] = __builtin_inff(); widx[r] = 1000;
        }
    }

    for (int k = 0; k < 10; k++) {
        float d = dist[0]; int wi = widx[0];
        if (dist[1] < d || (dist[1] == d && widx[1] < wi)) { d = dist[1]; wi = widx[1]; }
        #pragma unroll
        for (int off = 32; off >= 1; off >>= 1) {
            float od = __shfl_xor(d, off);
            int ow = __shfl_xor(wi, off);
            if (od < d || (od == d && ow < wi)) { d = od; wi = ow; }
        }
        if (lane == 0) {
            size_t ob = ((((size_t)t * 48 + i) * 48 + j) * 30 + dtIdx * 10 + k) * 3;
            out[ob + 0] = dtf;
            out[ob + 1] = fh + (float)(wi / 9 - 4);
            out[ob + 2] = fw + (float)(wi % 9 - 4);
        }
        if (widx[0] == wi) dist[0] = __builtin_inff();
        if (widx[1] == wi) dist[1] = __builtin_inff();
    }
}

// ---------------- host ----------------
extern "C" void kernel_launch(void* const* d_in, const int* in_sizes, int n_in,
                              void* d_out, int out_size, void* d_ws, size_t ws_size,
                              hipStream_t stream) {
    const float* vid = (const float*)d_in[0];
    const float* w1 = (const float*)d_in[1];  const float* b1 = (const float*)d_in[2];
    const float* w2 = (const float*)d_in[3];  const float* b2 = (const float*)d_in[4];
    const float* w3 = (const float*)d_in[5];  const float* b3 = (const float*)d_in[6];
    const float* w4 = (const float*)d_in[7];  const float* b4 = (const float*)d_in[8];
    const float* w5 = (const float*)d_in[9];  const float* b5 = (const float*)d_in[10];
    float* out = (float*)d_out;
    float* ws = (float*)d_ws;

    float* nv    = ws;                    //   442368
    float* pyr1  = nv    + 442368;        //   110592
    float* pyr2  = pyr1  + 110592;        //    27648
    float* pyr3  = pyr2  + 27648;         //     6912
    float* flowA = pyr3  + 6912;          //   442368 (6,2,192,192)
    float* flowB = flowA + 442368;        //   442368
    float* in8   = flowB + 442368;        //  1769472 (6,8,192,192)
    float* bufA  = in8   + 1769472;       //  7077888 (6,32,192,192)
    float* bufB  = bufA  + 7077888;       // 14155776 (6,64,192,192)

    k_normalize<<<(442368 + 255) / 256, 256, 0, stream>>>(vid, nv);
    k_pool<<<(110592 + 255) / 256, 256, 0, stream>>>(nv, pyr1, 12, 96, 96);
    k_pool<<<(27648 + 255) / 256, 256, 0, stream>>>(pyr1, pyr2, 12, 48, 48);
    k_pool<<<(6912 + 255) / 256, 256, 0, stream>>>(pyr2, pyr3, 12, 24, 24);

    const float* pyrs[4] = {nv, pyr1, pyr2, pyr3};

    float* cur = flowA;
    float* oth = flowB;
    hipMemsetAsync(cur, 0, (size_t)NBATCH * 2 * 24 * 24 * 4, stream);
    for (int l = 3; l >= 0; --l) {
        int H = H0 >> l, W = W0 >> l;
        if (l < 3) {
            k_upsample2x<<<((12 * H * W) + 255) / 256, 256, 0, stream>>>(cur, oth, 12, H / 2, W / 2);
            float* tsw = cur; cur = oth; oth = tsw;
        }
        k_build_in8<<<((NBATCH * H * W) + 255) / 256, 256, 0, stream>>>(pyrs[l], cur, in8, H, W);

        const float* W1 = w1 + (size_t)l * 32 * 8 * 49;  const float* B1 = b1 + l * 32;
        const float* W2 = w2 + (size_t)l * 64 * 32 * 49; const float* B2 = b2 + l * 64;
        const float* W3 = w3 + (size_t)l * 32 * 64 * 49; const float* B3 = b3 + l * 32;
        const float* W4 = w4 + (size_t)l * 16 * 32 * 49; const float* B4 = b4 + l * 16;
        const float* W5 = w5 + (size_t)l * 2 * 16 * 49;  const float* B5 = b5 + l * 2;

        int nt = (H + 31) / 32;
        int ntt = nt * nt;
        k_conv<4, true,  false><<<ntt * 8 * 6,  256, 0, stream>>>(in8,  W1, B1, bufA, 8,  32, H, W, nt, nt, 8);
        k_conv<4, true,  false><<<ntt * 16 * 6, 256, 0, stream>>>(bufA, W2, B2, bufB, 32, 64, H, W, nt, nt, 16);
        k_conv<4, true,  false><<<ntt * 8 * 6,  256, 0, stream>>>(bufB, W3, B3, bufA, 64, 32, H, W, nt, nt, 8);
        k_conv<4, true,  false><<<ntt * 4 * 6,  256, 0, stream>>>(bufA, W4, B4, bufB, 32, 16, H, W, nt, nt, 4);
        k_conv<2, false, true ><<<ntt * 1 * 6,  256, 0, stream>>>(bufB, W5, B5, cur,  16, 2,  H, W, nt, nt, 1);
    }

    k_match<<<27648, 64, 0, stream>>>(vid, cur, out);
}